// Round 1
// baseline (207.602 us; speedup 1.0000x reference)
//
#include <hip/hip_runtime.h>

// x: [8, 1, 160, 160, 160] fp32; log_sigma: [3] fp32; out: scalar fp32.
// loss = -(mean_d(k) + mean_h(k) + mean_w(k)) / 3, k = exp(-sq/(2*sigma^2)),
// sq[b][pair] = sum over remaining dims of adjacent-slice squared diff.

constexpr int Wd = 160;
constexpr int SLICE = 160 * 160;          // floats per (b,d) slice
constexpr long BSTRIDE = 160L * 25600;    // floats per batch
constexpr int NB = 8;
constexpr int NPAIR = 159;                // slice pairs per axis
constexpr int WS_FLOATS = 3 * NB * NPAIR; // 3816

__global__ void zero_ws_kernel(float* __restrict__ ws) {
    int i = blockIdx.x * 256 + threadIdx.x;
    if (i < WS_FLOATS) ws[i] = 0.f;
}

// Grid: 8 b * 10 h-chunks * 16 d-segments = 1280 blocks, 320 threads.
// Thread t: float4 column fw = t%40, rows r1 = t/40 (0..7) and r2 = r1+8.
// Block iterates slices d0..d0+nsl-1 (1 halo slice for d-diffs, except last seg).
__global__ __launch_bounds__(320) void diff3_kernel(const float* __restrict__ x,
                                                    float* __restrict__ ws) {
    __shared__ __align__(16) float buf[2][17 * Wd];  // current slice, 16 owned rows + 1 halo row
    __shared__ float accD[10];
    __shared__ float accH[16];
    __shared__ float accW[160];

    const int t = threadIdx.x;
    const int bid = blockIdx.x;
    const int b = bid / 160;
    const int rem = bid % 160;
    const int s = rem / 10;    // d-segment 0..15
    const int hc = rem % 10;   // h-chunk 0..9
    const int h0 = hc * 16;
    const int d0 = s * 10;
    const int nsl = (s < 15) ? 11 : 10;  // last segment has no halo slice

    const int fw = t % 40;
    const int r1 = t / 40;   // 0..7
    const int r2 = r1 + 8;   // 8..15
    const bool halo = (t < 40) && (hc < 9);  // last h-chunk has no halo row

    if (t < 10)  accD[t] = 0.f;
    if (t < 16)  accH[t] = 0.f;
    if (t < 160) accW[t] = 0.f;

    const float* xb = x + (size_t)b * BSTRIDE + (size_t)h0 * Wd + (size_t)fw * 4;

    float4 pv1, pv2;
    float aH1 = 0.f, aH2 = 0.f;
    float aW0 = 0.f, aW1 = 0.f, aW2 = 0.f, aW3 = 0.f;

    for (int it = 0; it < nsl; ++it) {
        const float* sp = xb + (size_t)(d0 + it) * SLICE;
        const float4 v1 = *(const float4*)(sp + r1 * Wd);
        const float4 v2 = *(const float4*)(sp + r2 * Wd);
        float4 v3;
        if (halo) v3 = *(const float4*)(sp + 16 * Wd);

        float* Bf = buf[it & 1];
        *(float4*)(Bf + r1 * Wd + fw * 4) = v1;
        *(float4*)(Bf + r2 * Wd + fw * 4) = v2;
        if (halo) *(float4*)(Bf + 16 * Wd + fw * 4) = v3;
        __syncthreads();

        // d-axis: diff vs previous slice (pair index d0+it-1), owned rows only
        if (it > 0) {
            float dx0 = v1.x - pv1.x, dx1 = v1.y - pv1.y, dx2 = v1.z - pv1.z, dx3 = v1.w - pv1.w;
            float dy0 = v2.x - pv2.x, dy1 = v2.y - pv2.y, dy2 = v2.z - pv2.z, dy3 = v2.w - pv2.w;
            float dd = dx0*dx0 + dx1*dx1 + dx2*dx2 + dx3*dx3
                     + dy0*dy0 + dy1*dy1 + dy2*dy2 + dy3*dy3;
            for (int off = 32; off > 0; off >>= 1) dd += __shfl_down(dd, off, 64);
            if ((t & 63) == 0) atomicAdd(&accD[it - 1], dd);
        }
        pv1 = v1; pv2 = v2;

        // w/h axes only for owned slices (it < 10)
        if (it < 10) {
            {   // row r1
                float dw;
                dw = v1.y - v1.x; aW0 += dw * dw;
                dw = v1.z - v1.y; aW1 += dw * dw;
                dw = v1.w - v1.z; aW2 += dw * dw;
                if (fw < 39) { dw = Bf[r1 * Wd + fw * 4 + 4] - v1.w; aW3 += dw * dw; }
                if (h0 + r1 < 159) {
                    const float4 hb = *(const float4*)(Bf + (r1 + 1) * Wd + fw * 4);
                    float e0 = hb.x - v1.x, e1 = hb.y - v1.y, e2 = hb.z - v1.z, e3 = hb.w - v1.w;
                    aH1 += e0*e0 + e1*e1 + e2*e2 + e3*e3;
                }
            }
            {   // row r2
                float dw;
                dw = v2.y - v2.x; aW0 += dw * dw;
                dw = v2.z - v2.y; aW1 += dw * dw;
                dw = v2.w - v2.z; aW2 += dw * dw;
                if (fw < 39) { dw = Bf[r2 * Wd + fw * 4 + 4] - v2.w; aW3 += dw * dw; }
                if (h0 + r2 < 159) {
                    const float4 hb = *(const float4*)(Bf + (r2 + 1) * Wd + fw * 4);
                    float e0 = hb.x - v2.x, e1 = hb.y - v2.y, e2 = hb.z - v2.z, e3 = hb.w - v2.w;
                    aH2 += e0*e0 + e1*e1 + e2*e2 + e3*e3;
                }
            }
        }
    }

    // flush per-thread register accumulators into LDS
    atomicAdd(&accH[r1], aH1);
    atomicAdd(&accH[r2], aH2);
    atomicAdd(&accW[fw * 4 + 0], aW0);
    atomicAdd(&accW[fw * 4 + 1], aW1);
    atomicAdd(&accW[fw * 4 + 2], aW2);
    if (fw < 39) atomicAdd(&accW[fw * 4 + 3], aW3);
    __syncthreads();

    // flush block accumulators to global workspace
    float* wsD = ws;
    float* wsH = ws + NB * NPAIR;
    float* wsW = ws + 2 * NB * NPAIR;
    const int nd = nsl - 1;
    if (t < nd) atomicAdd(&wsD[b * NPAIR + d0 + t], accD[t]);
    if (t >= 32 && t < 48) {
        int r = t - 32;
        if (h0 + r < 159) atomicAdd(&wsH[b * NPAIR + h0 + r], accH[r]);
    }
    if (t >= 64 && t < 64 + 159) {
        int k = t - 64;
        atomicAdd(&wsW[b * NPAIR + k], accW[k]);
    }
}

__global__ __launch_bounds__(256) void finalize_kernel(const float* __restrict__ ws,
                                                       const float* __restrict__ log_sigma,
                                                       float* __restrict__ out) {
    __shared__ float ssum;
    const int t = threadIdx.x;
    if (t == 0) ssum = 0.f;
    __syncthreads();

    const float f0 = -0.5f * expf(-2.f * log_sigma[0]);  // -1/(2*sigma0^2)
    const float f1 = -0.5f * expf(-2.f * log_sigma[1]);
    const float f2 = -0.5f * expf(-2.f * log_sigma[2]);

    float acc = 0.f;
    const int n = NB * NPAIR;  // 1272 per axis
    for (int i = t; i < n; i += 256) acc += expf(ws[i] * f0);
    for (int i = t; i < n; i += 256) acc += expf(ws[n + i] * f1);
    for (int i = t; i < n; i += 256) acc += expf(ws[2 * n + i] * f2);

    for (int off = 32; off > 0; off >>= 1) acc += __shfl_down(acc, off, 64);
    if ((t & 63) == 0) atomicAdd(&ssum, acc);
    __syncthreads();
    if (t == 0) out[0] = -ssum / (float)(3 * NB * NPAIR);
}

extern "C" void kernel_launch(void* const* d_in, const int* in_sizes, int n_in,
                              void* d_out, int out_size, void* d_ws, size_t ws_size,
                              hipStream_t stream) {
    const float* x = (const float*)d_in[0];
    const float* log_sigma = (const float*)d_in[1];
    float* out = (float*)d_out;
    float* ws = (float*)d_ws;

    zero_ws_kernel<<<(WS_FLOATS + 255) / 256, 256, 0, stream>>>(ws);
    diff3_kernel<<<8 * 10 * 16, 320, 0, stream>>>(x, ws);
    finalize_kernel<<<1, 256, 0, stream>>>(ws, log_sigma, out);
}